// Round 5
// baseline (177.747 us; speedup 1.0000x reference)
//
#include <hip/hip_runtime.h>
#include <stdint.h>

// Dims: msa[1,S,R,M] fp32 ; left_w/right_w[M,C] ; out_w[C*C,CZ] ; out[1,R,R,CZ] fp32
#define S_DIM 128
#define R_DIM 256
#define M_DIM 256
#define C_DIM 32
#define CZ_DIM 128
#define K2_DIM 1024  // C*C

typedef _Float16 f16;
typedef _Float16 f16x4 __attribute__((ext_vector_type(4)));
typedef _Float16 f16x8 __attribute__((ext_vector_type(8)));
typedef float f32x4 __attribute__((ext_vector_type(4)));
typedef float f32x16 __attribute__((ext_vector_type(16)));

// ---------------------------------------------------------------------------
// prep: weights -> f16. wt_l/wt_r[c][m]; wt_o[cz][k2] (plain transpose of ow).
// ---------------------------------------------------------------------------
__global__ void prep_kernel(const float* __restrict__ lw, const float* __restrict__ rw,
                            const float* __restrict__ ow,
                            f16* __restrict__ wt_l, f16* __restrict__ wt_r,
                            f16* __restrict__ wt_o) {
    int idx = blockIdx.x * blockDim.x + threadIdx.x;
    int stride = gridDim.x * blockDim.x;
    for (int i = idx; i < CZ_DIM * K2_DIM; i += stride) {
        int cz = i >> 10, k2 = i & 1023;
        wt_o[i] = (f16)ow[k2 * CZ_DIM + cz];
    }
    for (int i = idx; i < C_DIM * M_DIM; i += stride) {
        int c = i >> 8, m = i & 255;
        wt_l[i] = (f16)lw[m * C_DIM + c];
        wt_r[i] = (f16)rw[m * C_DIM + c];
    }
}

// ---------------------------------------------------------------------------
// proj (correctness-proven, near HBM floor): per block (r, s-half):
// D = wt(32 c x 256 m) @ msa_r^T (256 m x 64 s); writes left_t/right_t[(rc)][s].
// ---------------------------------------------------------------------------
__global__ __launch_bounds__(256, 4)
void proj_kernel(const float* __restrict__ msa, const f16* __restrict__ wt_l,
                 const f16* __restrict__ wt_r,
                 f16* __restrict__ left_t, f16* __restrict__ right_t) {
    int bid = blockIdx.x;            // 512 = 256 r * 2 s-halves
    int r  = bid >> 1;
    int s0 = (bid & 1) << 6;
    int tid = threadIdx.x;
    int w = tid >> 6;
    int lane = tid & 63;
    int q = lane >> 4, li = lane & 15;

    int s_col = s0 + w * 16 + li;
    const f32x4* bp = (const f32x4*)(msa + ((size_t)s_col * R_DIM + r) * M_DIM + q * 8);

    f32x4 b[16];
#pragma unroll
    for (int ks = 0; ks < 8; ks++) { b[2 * ks] = bp[ks * 8]; b[2 * ks + 1] = bp[ks * 8 + 1]; }

    f32x4 aL0 = {0,0,0,0}, aL1 = {0,0,0,0}, aR0 = {0,0,0,0}, aR1 = {0,0,0,0};
#pragma unroll
    for (int ks = 0; ks < 8; ks++) {
        f16x8 bf;
#pragma unroll
        for (int u = 0; u < 4; u++) { bf[u] = (f16)b[2*ks][u]; bf[4 + u] = (f16)b[2*ks+1][u]; }
        const f16* a0 = wt_l + li * M_DIM + ks * 32 + q * 8;
        const f16* a1 = wt_r + li * M_DIM + ks * 32 + q * 8;
        f16x8 al0 = *(const f16x8*)(a0);
        f16x8 al1 = *(const f16x8*)(a0 + 16 * M_DIM);
        f16x8 ar0 = *(const f16x8*)(a1);
        f16x8 ar1 = *(const f16x8*)(a1 + 16 * M_DIM);
        aL0 = __builtin_amdgcn_mfma_f32_16x16x32_f16(al0, bf, aL0, 0, 0, 0);
        aL1 = __builtin_amdgcn_mfma_f32_16x16x32_f16(al1, bf, aL1, 0, 0, 0);
        aR0 = __builtin_amdgcn_mfma_f32_16x16x32_f16(ar0, bf, aR0, 0, 0, 0);
        aR1 = __builtin_amdgcn_mfma_f32_16x16x32_f16(ar1, bf, aR1, 0, 0, 0);
    }
#pragma unroll
    for (int reg = 0; reg < 4; reg++) {
        int c0 = q * 4 + reg;
        left_t [(r * C_DIM + c0) * S_DIM + s_col]      = (f16)aL0[reg];
        left_t [(r * C_DIM + c0 + 16) * S_DIM + s_col] = (f16)aL1[reg];
        right_t[(r * C_DIM + c0) * S_DIM + s_col]      = (f16)aR0[reg];
        right_t[(r * C_DIM + c0 + 16) * S_DIM + s_col] = (f16)aR1[reg];
    }
}

// ---------------------------------------------------------------------------
// fuse_kernel: per block = 8r x 4t pair tile (32 pairs). Replaces outer+out.
//  phase0: stage left rows (256x128, 64KB) + right rows (128x128, 32KB) into
//          swizzled LDS (phys_ch = ch ^ (row&15), proven in R4 outer_kernel).
//  phase1: stage1 GEMM: D[te][rc] = right @ left^T via 32x32x16 MFMA.
//          Wave w: A tile = te tile (w&3), B tiles rc = 4*(w>>2)+i, i=0..3.
//          Accs (4x16 f32) stay in regs across the barrier.
//  phase2: outer (32 pairs x 1024 k2, f16) overlays the left-staging LDS.
//          Slot map (8B granularity): row p (2048B), logical slot = c*8+eg2,
//          phys = (c*8 + (eg2 ^ 2*((c>>2)&3)) + 2p) & 255. Even XOR keeps
//          b128 16B-alignment; +2p row rotation makes stage2 reads 2-way
//          (free); writes b64 4-way (16/wave, negligible).
//  phase3: stage2: out[p][cz] = outer @ wt_o^T via 16x16x32; wave w owns cz
//          tile w (W read exactly ONCE per block = 256KB from L2).
// ---------------------------------------------------------------------------
__global__ __launch_bounds__(512, 2)
void fuse_kernel(const f16* __restrict__ left_t, const f16* __restrict__ right_t,
                 const f16* __restrict__ wt_o, float* __restrict__ out) {
    __shared__ __align__(16) char lds[98304];           // 96 KiB
    f16* Ls = (f16*)lds;                                // 256x128 (overlaid later)
    f16* Rs = (f16*)(lds + 65536);                      // 128x128
    char* outerL = lds;                                 // 32 x 2048B

    int bid = blockIdx.x;        // 2048 = 32 br * 64 bt
    int br = bid >> 6, bt = bid & 63;
    int tid = threadIdx.x;
    int w = tid >> 6, lane = tid & 63;
    int q5 = lane >> 5, li = lane & 15, q = lane >> 4;

    const f16* Lg = left_t  + (size_t)br * 32768;       // 256 rc rows x 128 s
    const f16* Rg = right_t + (size_t)bt * 16384;       // 128 te rows x 128 s

    // ---- phase 0: stage ----
#pragma unroll
    for (int it = 0; it < 8; it++) {
        int G = it * 512 + tid, row = G >> 4, ch = G & 15;
        f16x8 v = *(const f16x8*)(Lg + G * 8);
        *(f16x8*)(Ls + row * 128 + ((ch ^ (row & 15)) << 3)) = v;
    }
#pragma unroll
    for (int it = 0; it < 4; it++) {
        int G = it * 512 + tid, row = G >> 4, ch = G & 15;
        f16x8 v = *(const f16x8*)(Rg + G * 8);
        *(f16x8*)(Rs + row * 128 + ((ch ^ (row & 15)) << 3)) = v;
    }
    __syncthreads();

    // ---- phase 1: stage1 MFMAs ----
    int t_tile = w & 3, rg4 = w >> 2;
    int l31 = lane & 31, lx = lane & 15;
    int arow = t_tile * 32 + l31;                       // te row (A)
    f16x8 afr[8];
#pragma unroll
    for (int ks = 0; ks < 8; ks++)
        afr[ks] = *(const f16x8*)(Rs + arow * 128 + (((2 * ks + q5) ^ lx) << 3));

    f32x16 acc[4] = {};
#pragma unroll
    for (int i = 0; i < 4; i++) {
        int brow = (rg4 * 4 + i) * 32 + l31;            // rc row (B)
#pragma unroll
        for (int ks = 0; ks < 8; ks++) {
            f16x8 bfr = *(const f16x8*)(Ls + brow * 128 + (((2 * ks + q5) ^ lx) << 3));
            acc[i] = __builtin_amdgcn_mfma_f32_32x32x16_f16(afr[ks], bfr, acc[i], 0, 0, 0);
        }
    }
    __syncthreads();

    // ---- phase 2: write outer to LDS (overlays Ls) ----
    // D: row = e = (reg&3) + 8*(reg>>2) + 4*q5 ; col = c = lane&31
    int c = l31;
    int swc = 2 * ((c >> 2) & 3);
#pragma unroll
    for (int i = 0; i < 4; i++) {
        int p = (rg4 * 4 + i) * 4 + t_tile;             // pair row 0..31
#pragma unroll
        for (int rg = 0; rg < 4; rg++) {
            int eg2 = 2 * rg + q5;
            int ps = (c * 8 + (eg2 ^ swc) + 2 * p) & 255;
            f16x4 h = {(f16)acc[i][4 * rg], (f16)acc[i][4 * rg + 1],
                       (f16)acc[i][4 * rg + 2], (f16)acc[i][4 * rg + 3]};
            *(f16x4*)(outerL + p * 2048 + ps * 8) = h;
        }
    }
    __syncthreads();

    // ---- phase 3: stage2 ----
    const f16* wrow = wt_o + (size_t)(w * 16 + li) * K2_DIM;
    f32x4 acc2[2] = {{0,0,0,0},{0,0,0,0}};
#pragma unroll 4
    for (int ks2 = 0; ks2 < 32; ks2++) {
        f16x8 wf = *(const f16x8*)(wrow + ks2 * 32 + q * 8);
        int sw2 = 2 * ((ks2 >> 2) & 3);
        int base = ks2 * 8 + ((2 * q) ^ sw2);
        int ps0 = (base + 2 * li) & 255;
        int ps1 = (base + 2 * (16 + li)) & 255;
        f16x8 a0 = *(const f16x8*)(outerL + li * 2048 + ps0 * 8);
        f16x8 a1 = *(const f16x8*)(outerL + (16 + li) * 2048 + ps1 * 8);
        acc2[0] = __builtin_amdgcn_mfma_f32_16x16x32_f16(a0, wf, acc2[0], 0, 0, 0);
        acc2[1] = __builtin_amdgcn_mfma_f32_16x16x32_f16(a1, wf, acc2[1], 0, 0, 0);
    }

    // store: D row = p = m2*16 + q*4 + reg, col = cz = w*16 + li
    int r0 = br * 8, t0 = bt * 4, cz = w * 16 + li;
#pragma unroll
    for (int m2 = 0; m2 < 2; m2++) {
#pragma unroll
        for (int reg = 0; reg < 4; reg++) {
            int p = m2 * 16 + q * 4 + reg;
            out[((size_t)((r0 + (p >> 2)) * R_DIM + t0 + (p & 3))) * CZ_DIM + cz] = acc2[m2][reg];
        }
    }
}

// ---------------------------------------------------------------------------
extern "C" void kernel_launch(void* const* d_in, const int* in_sizes, int n_in,
                              void* d_out, int out_size, void* d_ws, size_t ws_size,
                              hipStream_t stream) {
    const float* msa = (const float*)d_in[0];
    const float* lw  = (const float*)d_in[1];
    const float* rw  = (const float*)d_in[2];
    const float* ow  = (const float*)d_in[3];
    char* ws = (char*)d_ws;
    f16* left_t  = (f16*)(ws);                                   // 2 MB
    f16* right_t = (f16*)(ws + (size_t)2 * 1024 * 1024);         // 2 MB
    f16* wt_o    = (f16*)(ws + (size_t)4 * 1024 * 1024);         // 256 KB
    f16* wt_l    = (f16*)(ws + (size_t)4 * 1024 * 1024 + 262144);        // 16 KB
    f16* wt_r    = (f16*)(ws + (size_t)4 * 1024 * 1024 + 262144 + 16384);// 16 KB
    float* out   = (float*)d_out;

    prep_kernel<<<dim3(256), dim3(256), 0, stream>>>(lw, rw, ow, wt_l, wt_r, wt_o);
    proj_kernel<<<dim3(512), dim3(256), 0, stream>>>(msa, wt_l, wt_r, left_t, right_t);
    fuse_kernel<<<dim3(2048), dim3(512), 0, stream>>>(left_t, right_t, wt_o, out);
}

// Round 6
// 177.025 us; speedup vs baseline: 1.0041x; 1.0041x over previous
//
#include <hip/hip_runtime.h>
#include <stdint.h>

// Dims: msa[1,S,R,M] fp32 ; left_w/right_w[M,C] ; out_w[C*C,CZ] ; out[1,R,R,CZ] fp32
#define S_DIM 128
#define R_DIM 256
#define M_DIM 256
#define C_DIM 32
#define CZ_DIM 128
#define K2_DIM 1024  // C*C

typedef _Float16 f16;
typedef _Float16 f16x4 __attribute__((ext_vector_type(4)));
typedef _Float16 f16x8 __attribute__((ext_vector_type(8)));
typedef float f32x4 __attribute__((ext_vector_type(4)));
typedef float f32x16 __attribute__((ext_vector_type(16)));

// ---------------------------------------------------------------------------
// prep: weights -> f16. wt_l/wt_r[c][m]; wt_o[cz][k2'] where
// k2' = (e>>2)*128 + c*4 + (e&3)  (k2 = c*32+e). The k2' permutation matches
// the fused kernel's LDS outer layout (MFMA only needs pairwise k agreement).
// ---------------------------------------------------------------------------
__global__ void prep_kernel(const float* __restrict__ lw, const float* __restrict__ rw,
                            const float* __restrict__ ow,
                            f16* __restrict__ wt_l, f16* __restrict__ wt_r,
                            f16* __restrict__ wt_o) {
    int idx = blockIdx.x * blockDim.x + threadIdx.x;
    int stride = gridDim.x * blockDim.x;
    for (int i = idx; i < CZ_DIM * K2_DIM; i += stride) {
        int cz = i >> 10, k2 = i & 1023;
        int c = k2 >> 5, e = k2 & 31;
        int k2p = ((e >> 2) << 7) + (c << 2) + (e & 3);
        wt_o[(cz << 10) + k2p] = (f16)ow[k2 * CZ_DIM + cz];
    }
    for (int i = idx; i < C_DIM * M_DIM; i += stride) {
        int c = i >> 8, m = i & 255;
        wt_l[i] = (f16)lw[m * C_DIM + c];
        wt_r[i] = (f16)rw[m * C_DIM + c];
    }
}

// ---------------------------------------------------------------------------
// proj (correctness-proven, near HBM floor): per block (r, s-half):
// D = wt(32 c x 256 m) @ msa_r^T (256 m x 64 s); writes left_t/right_t[(rc)][s].
// ---------------------------------------------------------------------------
__global__ __launch_bounds__(256, 4)
void proj_kernel(const float* __restrict__ msa, const f16* __restrict__ wt_l,
                 const f16* __restrict__ wt_r,
                 f16* __restrict__ left_t, f16* __restrict__ right_t) {
    int bid = blockIdx.x;            // 512 = 256 r * 2 s-halves
    int r  = bid >> 1;
    int s0 = (bid & 1) << 6;
    int tid = threadIdx.x;
    int w = tid >> 6;
    int lane = tid & 63;
    int q = lane >> 4, li = lane & 15;

    int s_col = s0 + w * 16 + li;
    const f32x4* bp = (const f32x4*)(msa + ((size_t)s_col * R_DIM + r) * M_DIM + q * 8);

    f32x4 b[16];
#pragma unroll
    for (int ks = 0; ks < 8; ks++) { b[2 * ks] = bp[ks * 8]; b[2 * ks + 1] = bp[ks * 8 + 1]; }

    f32x4 aL0 = {0,0,0,0}, aL1 = {0,0,0,0}, aR0 = {0,0,0,0}, aR1 = {0,0,0,0};
#pragma unroll
    for (int ks = 0; ks < 8; ks++) {
        f16x8 bf;
#pragma unroll
        for (int u = 0; u < 4; u++) { bf[u] = (f16)b[2*ks][u]; bf[4 + u] = (f16)b[2*ks+1][u]; }
        const f16* a0 = wt_l + li * M_DIM + ks * 32 + q * 8;
        const f16* a1 = wt_r + li * M_DIM + ks * 32 + q * 8;
        f16x8 al0 = *(const f16x8*)(a0);
        f16x8 al1 = *(const f16x8*)(a0 + 16 * M_DIM);
        f16x8 ar0 = *(const f16x8*)(a1);
        f16x8 ar1 = *(const f16x8*)(a1 + 16 * M_DIM);
        aL0 = __builtin_amdgcn_mfma_f32_16x16x32_f16(al0, bf, aL0, 0, 0, 0);
        aL1 = __builtin_amdgcn_mfma_f32_16x16x32_f16(al1, bf, aL1, 0, 0, 0);
        aR0 = __builtin_amdgcn_mfma_f32_16x16x32_f16(ar0, bf, aR0, 0, 0, 0);
        aR1 = __builtin_amdgcn_mfma_f32_16x16x32_f16(ar1, bf, aR1, 0, 0, 0);
    }
#pragma unroll
    for (int reg = 0; reg < 4; reg++) {
        int c0 = q * 4 + reg;
        left_t [(r * C_DIM + c0) * S_DIM + s_col]      = (f16)aL0[reg];
        left_t [(r * C_DIM + c0 + 16) * S_DIM + s_col] = (f16)aL1[reg];
        right_t[(r * C_DIM + c0) * S_DIM + s_col]      = (f16)aR0[reg];
        right_t[(r * C_DIM + c0 + 16) * S_DIM + s_col] = (f16)aR1[reg];
    }
}

// ---------------------------------------------------------------------------
// fuse_kernel v2: per block = 8r x 4t pairs, 64KB LDS -> 2 blocks/CU.
//  phase0: prefetch afr (right rows, A-operand) from L2; stage left tile
//          (256x128 = 64KB) into swizzled LDS (phys_ch = ch ^ (row&15)).
//  phase1: stage1: wave w: te tile = w&3 (A, cached regs), rc tiles
//          rg4*4+i (B from LDS); 32x 32x32x16 MFMA; acc = 4 x f32x16.
//  phase2: outer overlays LDS: row p (2KB), k2' = (e>>2)*128+c*4+(e&3),
//          16B chunk phys = (ch + p) & 127.  b64 writes 2-way (free),
//          b128 reads 8-round optimal (bank math in journal).
//  phase3: stage2: out[p][cz] = outer @ wt_o^T, 32x32x16, wave = (cz tile
//          w&3, k-half w>>2); k-reduction pair (w, w+4) via 16KB LDS.
// ---------------------------------------------------------------------------
__global__ __launch_bounds__(512, 4)
void fuse_kernel(const f16* __restrict__ left_t, const f16* __restrict__ right_t,
                 const f16* __restrict__ wt_o, float* __restrict__ out) {
    __shared__ __align__(16) char lds[65536];
    f16* Ls = (f16*)lds;

    int bid = blockIdx.x;        // 2048 = 32 br * 64 bt
    int br = bid >> 6, bt = bid & 63;
    int tid = threadIdx.x;
    int w = tid >> 6, lane = tid & 63;
    int q5 = lane >> 5, l31 = lane & 31, lx = lane & 15;

    const f16* Lg = left_t  + (size_t)br * 32768;   // 256 rc rows x 128 s
    const f16* Rg = right_t + (size_t)bt * 16384;   // 128 te rows x 128 s

    // ---- phase 0: afr prefetch (global, pre-barrier) + stage left ----
    int t_tile = w & 3, rg4 = w >> 2;
    const f16* ap = Rg + (t_tile * 32 + l31) * 128;
    f16x8 afr[8];
#pragma unroll
    for (int ks = 0; ks < 8; ks++) afr[ks] = *(const f16x8*)(ap + ks * 16 + q5 * 8);

#pragma unroll
    for (int it = 0; it < 8; it++) {
        int G = it * 512 + tid, row = G >> 4, ch = G & 15;
        f16x8 v = *(const f16x8*)(Lg + G * 8);
        *(f16x8*)(Ls + row * 128 + ((ch ^ (row & 15)) << 3)) = v;
    }
    __syncthreads();

    // ---- phase 1: stage1 MFMAs (D[te][rc], m=te-local=e, n=rc-local=c) ----
    f32x16 acc[4] = {};
#pragma unroll
    for (int i = 0; i < 4; i++) {
        const f16* bbase = Ls + ((rg4 * 4 + i) * 32 + l31) * 128;
#pragma unroll
        for (int ks = 0; ks < 8; ks++) {
            f16x8 bfr = *(const f16x8*)(bbase + (((2 * ks + q5) ^ lx) << 3));
            acc[i] = __builtin_amdgcn_mfma_f32_32x32x16_f16(afr[ks], bfr, acc[i], 0, 0, 0);
        }
    }
    __syncthreads();

    // ---- phase 2: write outer to LDS (overlays left tile) ----
    // lane: c = l31; e = 8*rg + 4*q5 + j (j=0..3) -> k2' chunk ch = (2rg+q5)*16 + c/2
    int chc = l31 >> 1, bsub = 8 * (l31 & 1);
#pragma unroll
    for (int i = 0; i < 4; i++) {
        int p = (rg4 * 4 + i) * 4 + t_tile;         // pair row 0..31
        char* prow = lds + p * 2048;
#pragma unroll
        for (int rg = 0; rg < 4; rg++) {
            int ch = (2 * rg + q5) * 16 + chc;
            int phys = (ch + p) & 127;
            f16x4 h = {(f16)acc[i][4 * rg], (f16)acc[i][4 * rg + 1],
                       (f16)acc[i][4 * rg + 2], (f16)acc[i][4 * rg + 3]};
            *(f16x4*)(prow + phys * 16 + bsub) = h;
        }
    }
    __syncthreads();

    // ---- phase 3: stage2 (m=p, n=cz tile w&3, k-half w>>2) ----
    int ntile = w & 3, kh = w >> 2;
    const f16* wbase = wt_o + (size_t)(ntile * 32 + l31) * K2_DIM + kh * 512;
    const char* lbase = lds + l31 * 2048;           // p = l31
    f32x16 acc2 = {};
#pragma unroll 8
    for (int kk = 0; kk < 32; kk++) {
        int ks2 = kh * 32 + kk;
        f16x8 wf = *(const f16x8*)(wbase + kk * 16 + q5 * 8);
        int phys = (2 * ks2 + q5 + l31) & 127;
        f16x8 af = *(const f16x8*)(lbase + phys * 16);
        acc2 = __builtin_amdgcn_mfma_f32_32x32x16_f16(af, wf, acc2, 0, 0, 0);
    }
    __syncthreads();

    // ---- k-reduction: wave w+4 -> LDS, wave w adds ----
    if (w >= 4) {
        char* rb = lds + (w - 4) * 4096 + lane * 64;
#pragma unroll
        for (int u = 0; u < 4; u++) {
            f32x4 part = {acc2[4 * u], acc2[4 * u + 1], acc2[4 * u + 2], acc2[4 * u + 3]};
            *(f32x4*)(rb + u * 16) = part;
        }
    }
    __syncthreads();
    if (w < 4) {
        const char* rb = lds + w * 4096 + lane * 64;
#pragma unroll
        for (int u = 0; u < 4; u++) {
            f32x4 part = *(const f32x4*)(rb + u * 16);
#pragma unroll
            for (int v = 0; v < 4; v++) acc2[4 * u + v] += part[v];
        }
        // store: D row = p = (reg&3)+8*(reg>>2)+4*q5 ; col = cz = w*32 + l31
        int r0 = br * 8, t0 = bt * 4, cz = w * 32 + l31;
#pragma unroll
        for (int reg = 0; reg < 16; reg++) {
            int p = (reg & 3) + 8 * (reg >> 2) + 4 * q5;
            out[((size_t)((r0 + (p >> 2)) * R_DIM + t0 + (p & 3))) * CZ_DIM + cz] = acc2[reg];
        }
    }
}

// ---------------------------------------------------------------------------
extern "C" void kernel_launch(void* const* d_in, const int* in_sizes, int n_in,
                              void* d_out, int out_size, void* d_ws, size_t ws_size,
                              hipStream_t stream) {
    const float* msa = (const float*)d_in[0];
    const float* lw  = (const float*)d_in[1];
    const float* rw  = (const float*)d_in[2];
    const float* ow  = (const float*)d_in[3];
    char* ws = (char*)d_ws;
    f16* left_t  = (f16*)(ws);                                   // 2 MB
    f16* right_t = (f16*)(ws + (size_t)2 * 1024 * 1024);         // 2 MB
    f16* wt_o    = (f16*)(ws + (size_t)4 * 1024 * 1024);         // 256 KB
    f16* wt_l    = (f16*)(ws + (size_t)4 * 1024 * 1024 + 262144);        // 16 KB
    f16* wt_r    = (f16*)(ws + (size_t)4 * 1024 * 1024 + 262144 + 16384);// 16 KB
    float* out   = (float*)d_out;

    prep_kernel<<<dim3(256), dim3(256), 0, stream>>>(lw, rw, ow, wt_l, wt_r, wt_o);
    proj_kernel<<<dim3(512), dim3(256), 0, stream>>>(msa, wt_l, wt_r, left_t, right_t);
    fuse_kernel<<<dim3(2048), dim3(512), 0, stream>>>(left_t, right_t, wt_o, out);
}

// Round 7
// 173.816 us; speedup vs baseline: 1.0226x; 1.0185x over previous
//
#include <hip/hip_runtime.h>
#include <stdint.h>

// Dims: msa[1,S,R,M] fp32 ; left_w/right_w[M,C] ; out_w[C*C,CZ] ; out[1,R,R,CZ] fp32
#define S_DIM 128
#define R_DIM 256
#define M_DIM 256
#define C_DIM 32
#define CZ_DIM 128
#define K2_DIM 1024  // C*C

typedef _Float16 f16;
typedef _Float16 f16x4 __attribute__((ext_vector_type(4)));
typedef _Float16 f16x8 __attribute__((ext_vector_type(8)));
typedef float f32x4 __attribute__((ext_vector_type(4)));
typedef float f32x16 __attribute__((ext_vector_type(16)));

// ---------------------------------------------------------------------------
// prep: weights -> f16. wt_l/wt_r[c][m]; wt_o[cz][k2'] where
// k2' = (e>>2)*128 + c*4 + (e&3)  (k2 = c*32+e), matching the fused kernel's
// LDS outer layout (MFMA only needs pairwise k agreement).
// ---------------------------------------------------------------------------
__global__ void prep_kernel(const float* __restrict__ lw, const float* __restrict__ rw,
                            const float* __restrict__ ow,
                            f16* __restrict__ wt_l, f16* __restrict__ wt_r,
                            f16* __restrict__ wt_o) {
    int idx = blockIdx.x * blockDim.x + threadIdx.x;
    int stride = gridDim.x * blockDim.x;
    for (int i = idx; i < CZ_DIM * K2_DIM; i += stride) {
        int cz = i >> 10, k2 = i & 1023;
        int c = k2 >> 5, e = k2 & 31;
        int k2p = ((e >> 2) << 7) + (c << 2) + (e & 3);
        wt_o[(cz << 10) + k2p] = (f16)ow[k2 * CZ_DIM + cz];
    }
    for (int i = idx; i < C_DIM * M_DIM; i += stride) {
        int c = i >> 8, m = i & 255;
        wt_l[i] = (f16)lw[m * C_DIM + c];
        wt_r[i] = (f16)rw[m * C_DIM + c];
    }
}

// ---------------------------------------------------------------------------
// proj (correctness-proven, near HBM floor): per block (r, s-half):
// D = wt(32 c x 256 m) @ msa_r^T (256 m x 64 s); writes left_t/right_t[(rc)][s].
// ---------------------------------------------------------------------------
__global__ __launch_bounds__(256, 4)
void proj_kernel(const float* __restrict__ msa, const f16* __restrict__ wt_l,
                 const f16* __restrict__ wt_r,
                 f16* __restrict__ left_t, f16* __restrict__ right_t) {
    int bid = blockIdx.x;            // 512 = 256 r * 2 s-halves
    int r  = bid >> 1;
    int s0 = (bid & 1) << 6;
    int tid = threadIdx.x;
    int w = tid >> 6;
    int lane = tid & 63;
    int q = lane >> 4, li = lane & 15;

    int s_col = s0 + w * 16 + li;
    const f32x4* bp = (const f32x4*)(msa + ((size_t)s_col * R_DIM + r) * M_DIM + q * 8);

    f32x4 b[16];
#pragma unroll
    for (int ks = 0; ks < 8; ks++) { b[2 * ks] = bp[ks * 8]; b[2 * ks + 1] = bp[ks * 8 + 1]; }

    f32x4 aL0 = {0,0,0,0}, aL1 = {0,0,0,0}, aR0 = {0,0,0,0}, aR1 = {0,0,0,0};
#pragma unroll
    for (int ks = 0; ks < 8; ks++) {
        f16x8 bf;
#pragma unroll
        for (int u = 0; u < 4; u++) { bf[u] = (f16)b[2*ks][u]; bf[4 + u] = (f16)b[2*ks+1][u]; }
        const f16* a0 = wt_l + li * M_DIM + ks * 32 + q * 8;
        const f16* a1 = wt_r + li * M_DIM + ks * 32 + q * 8;
        f16x8 al0 = *(const f16x8*)(a0);
        f16x8 al1 = *(const f16x8*)(a0 + 16 * M_DIM);
        f16x8 ar0 = *(const f16x8*)(a1);
        f16x8 ar1 = *(const f16x8*)(a1 + 16 * M_DIM);
        aL0 = __builtin_amdgcn_mfma_f32_16x16x32_f16(al0, bf, aL0, 0, 0, 0);
        aL1 = __builtin_amdgcn_mfma_f32_16x16x32_f16(al1, bf, aL1, 0, 0, 0);
        aR0 = __builtin_amdgcn_mfma_f32_16x16x32_f16(ar0, bf, aR0, 0, 0, 0);
        aR1 = __builtin_amdgcn_mfma_f32_16x16x32_f16(ar1, bf, aR1, 0, 0, 0);
    }
#pragma unroll
    for (int reg = 0; reg < 4; reg++) {
        int c0 = q * 4 + reg;
        left_t [(r * C_DIM + c0) * S_DIM + s_col]      = (f16)aL0[reg];
        left_t [(r * C_DIM + c0 + 16) * S_DIM + s_col] = (f16)aL1[reg];
        right_t[(r * C_DIM + c0) * S_DIM + s_col]      = (f16)aR0[reg];
        right_t[(r * C_DIM + c0 + 16) * S_DIM + s_col] = (f16)aR1[reg];
    }
}

// ---------------------------------------------------------------------------
// fuse_kernel v3: per block = 8r x 4t pairs, 64KB LDS, 2 blocks/CU.
//  phase0: prefetch afr (right rows) from L2; stage left tile into LDS.
//  phase1: stage1 32x32x16 MFMAs, 4 independent acc chains per wave.
//  phase2: outer -> LDS, k2' = (e>>2)*128+c*4+(e&3), chunk phys=(ch+p)&127.
//  phase3 (NEW): dual accumulator chains (even/odd k-step) + 2-deep W
//          register pipeline; W group 0 issued before the phase-2 barrier.
// ---------------------------------------------------------------------------
__global__ __launch_bounds__(512, 4)
void fuse_kernel(const f16* __restrict__ left_t, const f16* __restrict__ right_t,
                 const f16* __restrict__ wt_o, float* __restrict__ out) {
    __shared__ __align__(16) char lds[65536];
    f16* Ls = (f16*)lds;

    int bid = blockIdx.x;        // 2048 = 32 br * 64 bt
    int br = bid >> 6, bt = bid & 63;
    int tid = threadIdx.x;
    int w = tid >> 6, lane = tid & 63;
    int q5 = lane >> 5, l31 = lane & 31, lx = lane & 15;

    const f16* Lg = left_t  + (size_t)br * 32768;   // 256 rc rows x 128 s
    const f16* Rg = right_t + (size_t)bt * 16384;   // 128 te rows x 128 s

    // ---- phase 0: afr prefetch (global, pre-barrier) + stage left ----
    int t_tile = w & 3, rg4 = w >> 2;
    const f16* ap = Rg + (t_tile * 32 + l31) * 128;
    f16x8 afr[8];
#pragma unroll
    for (int ks = 0; ks < 8; ks++) afr[ks] = *(const f16x8*)(ap + ks * 16 + q5 * 8);

#pragma unroll
    for (int it = 0; it < 8; it++) {
        int G = it * 512 + tid, row = G >> 4, ch = G & 15;
        f16x8 v = *(const f16x8*)(Lg + G * 8);
        *(f16x8*)(Ls + row * 128 + ((ch ^ (row & 15)) << 3)) = v;
    }
    __syncthreads();

    // ---- phase 1: stage1 MFMAs (D[te][rc]) ----
    f32x16 acc[4] = {};
#pragma unroll
    for (int i = 0; i < 4; i++) {
        const f16* bbase = Ls + ((rg4 * 4 + i) * 32 + l31) * 128;
#pragma unroll
        for (int ks = 0; ks < 8; ks++) {
            f16x8 bfr = *(const f16x8*)(bbase + (((2 * ks + q5) ^ lx) << 3));
            acc[i] = __builtin_amdgcn_mfma_f32_32x32x16_f16(afr[ks], bfr, acc[i], 0, 0, 0);
        }
    }

    // ---- phase 3 W group 0: issue NOW (global, hidden by phase 2 + barrier) ----
    int ntile = w & 3, kh = w >> 2;
    const f16* wbase = wt_o + (size_t)(ntile * 32 + l31) * K2_DIM + kh * 512;
    f16x8 wfc[4], wfn[4];
#pragma unroll
    for (int u = 0; u < 4; u++) wfc[u] = *(const f16x8*)(wbase + u * 16 + q5 * 8);

    __syncthreads();   // protects LDS overlay (phase2 writes over Ls)

    // ---- phase 2: write outer to LDS ----
    int chc = l31 >> 1, bsub = 8 * (l31 & 1);
#pragma unroll
    for (int i = 0; i < 4; i++) {
        int p = (rg4 * 4 + i) * 4 + t_tile;         // pair row 0..31
        char* prow = lds + p * 2048;
#pragma unroll
        for (int rg = 0; rg < 4; rg++) {
            int ch = (2 * rg + q5) * 16 + chc;
            int phys = (ch + p) & 127;
            f16x4 h = {(f16)acc[i][4 * rg], (f16)acc[i][4 * rg + 1],
                       (f16)acc[i][4 * rg + 2], (f16)acc[i][4 * rg + 3]};
            *(f16x4*)(prow + phys * 16 + bsub) = h;
        }
    }
    __syncthreads();

    // ---- phase 3: stage2, dual chains + 2-deep W pipeline ----
    const char* lbase = lds + l31 * 2048;           // p = l31
    f32x16 accA = {}, accB = {};
#pragma unroll 1
    for (int g = 0; g < 8; g++) {
        int k0 = g * 4;
        if (g < 7) {
#pragma unroll
            for (int u = 0; u < 4; u++)
                wfn[u] = *(const f16x8*)(wbase + (k0 + 4 + u) * 16 + q5 * 8);
        }
        f16x8 af[4];
#pragma unroll
        for (int u = 0; u < 4; u++) {
            int ks2 = kh * 32 + k0 + u;
            int phys = (2 * ks2 + q5 + l31) & 127;
            af[u] = *(const f16x8*)(lbase + phys * 16);
        }
        accA = __builtin_amdgcn_mfma_f32_32x32x16_f16(af[0], wfc[0], accA, 0, 0, 0);
        accB = __builtin_amdgcn_mfma_f32_32x32x16_f16(af[1], wfc[1], accB, 0, 0, 0);
        accA = __builtin_amdgcn_mfma_f32_32x32x16_f16(af[2], wfc[2], accA, 0, 0, 0);
        accB = __builtin_amdgcn_mfma_f32_32x32x16_f16(af[3], wfc[3], accB, 0, 0, 0);
#pragma unroll
        for (int u = 0; u < 4; u++) wfc[u] = wfn[u];
    }
    f32x16 acc2;
#pragma unroll
    for (int v = 0; v < 16; v++) acc2[v] = accA[v] + accB[v];
    __syncthreads();

    // ---- k-reduction: wave w+4 -> LDS, wave w adds ----
    if (w >= 4) {
        char* rb = lds + (w - 4) * 4096 + lane * 64;
#pragma unroll
        for (int u = 0; u < 4; u++) {
            f32x4 part = {acc2[4 * u], acc2[4 * u + 1], acc2[4 * u + 2], acc2[4 * u + 3]};
            *(f32x4*)(rb + u * 16) = part;
        }
    }
    __syncthreads();
    if (w < 4) {
        const char* rb = lds + w * 4096 + lane * 64;
#pragma unroll
        for (int u = 0; u < 4; u++) {
            f32x4 part = *(const f32x4*)(rb + u * 16);
#pragma unroll
            for (int v = 0; v < 4; v++) acc2[4 * u + v] += part[v];
        }
        // store: D row = p = (reg&3)+8*(reg>>2)+4*q5 ; col = cz = w*32 + l31
        int r0 = br * 8, t0 = bt * 4, cz = w * 32 + l31;
#pragma unroll
        for (int reg = 0; reg < 16; reg++) {
            int p = (reg & 3) + 8 * (reg >> 2) + 4 * q5;
            out[((size_t)((r0 + (p >> 2)) * R_DIM + t0 + (p & 3))) * CZ_DIM + cz] = acc2[reg];
        }
    }
}

// ---------------------------------------------------------------------------
extern "C" void kernel_launch(void* const* d_in, const int* in_sizes, int n_in,
                              void* d_out, int out_size, void* d_ws, size_t ws_size,
                              hipStream_t stream) {
    const float* msa = (const float*)d_in[0];
    const float* lw  = (const float*)d_in[1];
    const float* rw  = (const float*)d_in[2];
    const float* ow  = (const float*)d_in[3];
    char* ws = (char*)d_ws;
    f16* left_t  = (f16*)(ws);                                   // 2 MB
    f16* right_t = (f16*)(ws + (size_t)2 * 1024 * 1024);         // 2 MB
    f16* wt_o    = (f16*)(ws + (size_t)4 * 1024 * 1024);         // 256 KB
    f16* wt_l    = (f16*)(ws + (size_t)4 * 1024 * 1024 + 262144);        // 16 KB
    f16* wt_r    = (f16*)(ws + (size_t)4 * 1024 * 1024 + 262144 + 16384);// 16 KB
    float* out   = (float*)d_out;

    prep_kernel<<<dim3(256), dim3(256), 0, stream>>>(lw, rw, ow, wt_l, wt_r, wt_o);
    proj_kernel<<<dim3(512), dim3(256), 0, stream>>>(msa, wt_l, wt_r, left_t, right_t);
    fuse_kernel<<<dim3(2048), dim3(512), 0, stream>>>(left_t, right_t, wt_o, out);
}

// Round 8
// 144.905 us; speedup vs baseline: 1.2266x; 1.1995x over previous
//
#include <hip/hip_runtime.h>
#include <stdint.h>

// Dims: msa[1,S,R,M] fp32 ; left_w/right_w[M,C] ; out_w[C*C,CZ] ; out[1,R,R,CZ] fp32
#define S_DIM 128
#define R_DIM 256
#define M_DIM 256
#define C_DIM 32
#define CZ_DIM 128
#define K2_DIM 1024  // C*C

typedef _Float16 f16;
typedef _Float16 f16x4 __attribute__((ext_vector_type(4)));
typedef _Float16 f16x8 __attribute__((ext_vector_type(8)));
typedef float f32x4 __attribute__((ext_vector_type(4)));
typedef float f32x16 __attribute__((ext_vector_type(16)));

// ---------------------------------------------------------------------------
// prep: weights -> f16.
//  wt_l/wt_r[c][m] (proj A-operands).
//  wt2 = out_w in stage2 B-FRAGMENT-MAJOR order: for cz (ntile=cz>>5,l31=cz&31)
//  and permuted k2' = (e>>2)*128+c*4+(e&3) (kk=k2'>>4, q5=(k2'>>3)&1, j=k2'&7):
//  idx = (ntile*64+kk)*512 + (l31*2+q5)*8 + j. A wave's load of step kk is then
//  1KB fully contiguous (lane = q5*32+l31) -> coalesced, no L1 gather.
// ---------------------------------------------------------------------------
__global__ void prep_kernel(const float* __restrict__ lw, const float* __restrict__ rw,
                            const float* __restrict__ ow,
                            f16* __restrict__ wt_l, f16* __restrict__ wt_r,
                            f16* __restrict__ wt2) {
    int idx = blockIdx.x * blockDim.x + threadIdx.x;
    int stride = gridDim.x * blockDim.x;
    for (int i = idx; i < CZ_DIM * K2_DIM; i += stride) {
        int cz = i >> 10, k2 = i & 1023;
        int c = k2 >> 5, e = k2 & 31;
        int k2p = ((e >> 2) << 7) + (c << 2) + (e & 3);
        int ntile = cz >> 5, l31 = cz & 31;
        int kk = k2p >> 4, q5 = (k2p >> 3) & 1, j = k2p & 7;
        wt2[(ntile * 64 + kk) * 512 + (l31 * 2 + q5) * 8 + j] = (f16)ow[k2 * CZ_DIM + cz];
    }
    for (int i = idx; i < C_DIM * M_DIM; i += stride) {
        int c = i >> 8, m = i & 255;
        wt_l[i] = (f16)lw[m * C_DIM + c];
        wt_r[i] = (f16)rw[m * C_DIM + c];
    }
}

// ---------------------------------------------------------------------------
// proj: per block (r, s-half): D = wt(32 c x 256 m) @ msa_r^T (256 m x 64 s).
// left_t[(r*32+c)][s] row-major (fuse stages it coalescedly).
// rt2 = right in stage1 A-FRAGMENT-MAJOR order: row te = r*32+c (g=r, l31=c),
// s = ks*16+q5*8+j -> idx = (r*8+ks)*512 + (c*2+q5)*8 + j; a wave's afr load
// is 1KB contiguous.
// ---------------------------------------------------------------------------
__global__ __launch_bounds__(256, 4)
void proj_kernel(const float* __restrict__ msa, const f16* __restrict__ wt_l,
                 const f16* __restrict__ wt_r,
                 f16* __restrict__ left_t, f16* __restrict__ rt2) {
    int bid = blockIdx.x;            // 512 = 256 r * 2 s-halves
    int r  = bid >> 1;
    int s0 = (bid & 1) << 6;
    int tid = threadIdx.x;
    int w = tid >> 6;
    int lane = tid & 63;
    int q = lane >> 4, li = lane & 15;

    int s_col = s0 + w * 16 + li;
    const f32x4* bp = (const f32x4*)(msa + ((size_t)s_col * R_DIM + r) * M_DIM + q * 8);

    f32x4 b[16];
#pragma unroll
    for (int ks = 0; ks < 8; ks++) { b[2 * ks] = bp[ks * 8]; b[2 * ks + 1] = bp[ks * 8 + 1]; }

    f32x4 aL0 = {0,0,0,0}, aL1 = {0,0,0,0}, aR0 = {0,0,0,0}, aR1 = {0,0,0,0};
#pragma unroll
    for (int ks = 0; ks < 8; ks++) {
        f16x8 bf;
#pragma unroll
        for (int u = 0; u < 4; u++) { bf[u] = (f16)b[2*ks][u]; bf[4 + u] = (f16)b[2*ks+1][u]; }
        const f16* a0 = wt_l + li * M_DIM + ks * 32 + q * 8;
        const f16* a1 = wt_r + li * M_DIM + ks * 32 + q * 8;
        f16x8 al0 = *(const f16x8*)(a0);
        f16x8 al1 = *(const f16x8*)(a0 + 16 * M_DIM);
        f16x8 ar0 = *(const f16x8*)(a1);
        f16x8 ar1 = *(const f16x8*)(a1 + 16 * M_DIM);
        aL0 = __builtin_amdgcn_mfma_f32_16x16x32_f16(al0, bf, aL0, 0, 0, 0);
        aL1 = __builtin_amdgcn_mfma_f32_16x16x32_f16(al1, bf, aL1, 0, 0, 0);
        aR0 = __builtin_amdgcn_mfma_f32_16x16x32_f16(ar0, bf, aR0, 0, 0, 0);
        aR1 = __builtin_amdgcn_mfma_f32_16x16x32_f16(ar1, bf, aR1, 0, 0, 0);
    }
    int ks_s = s_col >> 4, q5_s = (s_col >> 3) & 1, j_s = s_col & 7;
    int sbase = (r * 8 + ks_s) * 512 + q5_s * 8 + j_s;
#pragma unroll
    for (int reg = 0; reg < 4; reg++) {
        int c0 = q * 4 + reg;
        left_t[(r * C_DIM + c0) * S_DIM + s_col]      = (f16)aL0[reg];
        left_t[(r * C_DIM + c0 + 16) * S_DIM + s_col] = (f16)aL1[reg];
        rt2[sbase + c0 * 16]        = (f16)aR0[reg];   // (c0*2)*8
        rt2[sbase + (c0 + 16) * 16] = (f16)aR1[reg];
    }
}

// ---------------------------------------------------------------------------
// fuse_kernel v4: identical structure to v3; ONLY the afr and W global loads
// switched to fragment-major coalesced layouts (rt2, wt2).
// ---------------------------------------------------------------------------
__global__ __launch_bounds__(512, 4)
void fuse_kernel(const f16* __restrict__ left_t, const f16* __restrict__ rt2,
                 const f16* __restrict__ wt2, float* __restrict__ out) {
    __shared__ __align__(16) char lds[65536];
    f16* Ls = (f16*)lds;

    int bid = blockIdx.x;        // 2048 = 32 br * 64 bt
    int br = bid >> 6, bt = bid & 63;
    int tid = threadIdx.x;
    int w = tid >> 6, lane = tid & 63;
    int q5 = lane >> 5, l31 = lane & 31, lx = lane & 15;

    const f16* Lg = left_t + (size_t)br * 32768;    // 256 rc rows x 128 s

    // ---- phase 0: afr prefetch (coalesced fragment-major) + stage left ----
    int t_tile = w & 3, rg4 = w >> 2;
    int g = bt * 4 + t_tile;
    const f16* ap = rt2 + (size_t)g * 4096 + (l31 * 2 + q5) * 8;
    f16x8 afr[8];
#pragma unroll
    for (int ks = 0; ks < 8; ks++) afr[ks] = *(const f16x8*)(ap + ks * 512);

#pragma unroll
    for (int it = 0; it < 8; it++) {
        int G = it * 512 + tid, row = G >> 4, ch = G & 15;
        f16x8 v = *(const f16x8*)(Lg + G * 8);
        *(f16x8*)(Ls + row * 128 + ((ch ^ (row & 15)) << 3)) = v;
    }
    __syncthreads();

    // ---- phase 1: stage1 MFMAs (D[te][rc]) ----
    f32x16 acc[4] = {};
#pragma unroll
    for (int i = 0; i < 4; i++) {
        const f16* bbase = Ls + ((rg4 * 4 + i) * 32 + l31) * 128;
#pragma unroll
        for (int ks = 0; ks < 8; ks++) {
            f16x8 bfr = *(const f16x8*)(bbase + (((2 * ks + q5) ^ lx) << 3));
            acc[i] = __builtin_amdgcn_mfma_f32_32x32x16_f16(afr[ks], bfr, acc[i], 0, 0, 0);
        }
    }

    // ---- phase 3 W group 0: issue NOW (coalesced; hidden by phase2+barrier) ----
    int ntile = w & 3, kh = w >> 2;
    const f16* wbase = wt2 + (size_t)(ntile * 64 + kh * 32) * 512 + (l31 * 2 + q5) * 8;
    f16x8 wfc[4], wfn[4];
#pragma unroll
    for (int u = 0; u < 4; u++) wfc[u] = *(const f16x8*)(wbase + u * 512);

    __syncthreads();   // protects LDS overlay (phase2 writes over Ls)

    // ---- phase 2: write outer to LDS ----
    int chc = l31 >> 1, bsub = 8 * (l31 & 1);
#pragma unroll
    for (int i = 0; i < 4; i++) {
        int p = (rg4 * 4 + i) * 4 + t_tile;         // pair row 0..31
        char* prow = lds + p * 2048;
#pragma unroll
        for (int rg = 0; rg < 4; rg++) {
            int ch = (2 * rg + q5) * 16 + chc;
            int phys = (ch + p) & 127;
            f16x4 h = {(f16)acc[i][4 * rg], (f16)acc[i][4 * rg + 1],
                       (f16)acc[i][4 * rg + 2], (f16)acc[i][4 * rg + 3]};
            *(f16x4*)(prow + phys * 16 + bsub) = h;
        }
    }
    __syncthreads();

    // ---- phase 3: stage2, dual chains + 2-deep W pipeline ----
    const char* lbase = lds + l31 * 2048;           // p = l31
    f32x16 accA = {}, accB = {};
#pragma unroll 1
    for (int gg = 0; gg < 8; gg++) {
        int k0 = gg * 4;
        if (gg < 7) {
#pragma unroll
            for (int u = 0; u < 4; u++)
                wfn[u] = *(const f16x8*)(wbase + (k0 + 4 + u) * 512);
        }
        f16x8 af[4];
#pragma unroll
        for (int u = 0; u < 4; u++) {
            int ks2 = kh * 32 + k0 + u;
            int phys = (2 * ks2 + q5 + l31) & 127;
            af[u] = *(const f16x8*)(lbase + phys * 16);
        }
        accA = __builtin_amdgcn_mfma_f32_32x32x16_f16(af[0], wfc[0], accA, 0, 0, 0);
        accB = __builtin_amdgcn_mfma_f32_32x32x16_f16(af[1], wfc[1], accB, 0, 0, 0);
        accA = __builtin_amdgcn_mfma_f32_32x32x16_f16(af[2], wfc[2], accA, 0, 0, 0);
        accB = __builtin_amdgcn_mfma_f32_32x32x16_f16(af[3], wfc[3], accB, 0, 0, 0);
#pragma unroll
        for (int u = 0; u < 4; u++) wfc[u] = wfn[u];
    }
    f32x16 acc2;
#pragma unroll
    for (int v = 0; v < 16; v++) acc2[v] = accA[v] + accB[v];
    __syncthreads();

    // ---- k-reduction: wave w+4 -> LDS, wave w adds ----
    if (w >= 4) {
        char* rb = lds + (w - 4) * 4096 + lane * 64;
#pragma unroll
        for (int u = 0; u < 4; u++) {
            f32x4 part = {acc2[4 * u], acc2[4 * u + 1], acc2[4 * u + 2], acc2[4 * u + 3]};
            *(f32x4*)(rb + u * 16) = part;
        }
    }
    __syncthreads();
    if (w < 4) {
        const char* rb = lds + w * 4096 + lane * 64;
#pragma unroll
        for (int u = 0; u < 4; u++) {
            f32x4 part = *(const f32x4*)(rb + u * 16);
#pragma unroll
            for (int v = 0; v < 4; v++) acc2[4 * u + v] += part[v];
        }
        // store: D row = p = (reg&3)+8*(reg>>2)+4*q5 ; col = cz = w*32 + l31
        int r0 = br * 8, t0 = bt * 4, cz = w * 32 + l31;
#pragma unroll
        for (int reg = 0; reg < 16; reg++) {
            int p = (reg & 3) + 8 * (reg >> 2) + 4 * q5;
            out[((size_t)((r0 + (p >> 2)) * R_DIM + t0 + (p & 3))) * CZ_DIM + cz] = acc2[reg];
        }
    }
}

// ---------------------------------------------------------------------------
extern "C" void kernel_launch(void* const* d_in, const int* in_sizes, int n_in,
                              void* d_out, int out_size, void* d_ws, size_t ws_size,
                              hipStream_t stream) {
    const float* msa = (const float*)d_in[0];
    const float* lw  = (const float*)d_in[1];
    const float* rw  = (const float*)d_in[2];
    const float* ow  = (const float*)d_in[3];
    char* ws = (char*)d_ws;
    f16* left_t = (f16*)(ws);                                   // 2 MB
    f16* rt2    = (f16*)(ws + (size_t)2 * 1024 * 1024);         // 2 MB
    f16* wt2    = (f16*)(ws + (size_t)4 * 1024 * 1024);         // 256 KB
    f16* wt_l   = (f16*)(ws + (size_t)4 * 1024 * 1024 + 262144);        // 16 KB
    f16* wt_r   = (f16*)(ws + (size_t)4 * 1024 * 1024 + 262144 + 16384);// 16 KB
    float* out  = (float*)d_out;

    prep_kernel<<<dim3(256), dim3(256), 0, stream>>>(lw, rw, ow, wt_l, wt_r, wt2);
    proj_kernel<<<dim3(512), dim3(256), 0, stream>>>(msa, wt_l, wt_r, left_t, rt2);
    fuse_kernel<<<dim3(2048), dim3(512), 0, stream>>>(left_t, rt2, wt2, out);
}

// Round 9
// 136.109 us; speedup vs baseline: 1.3059x; 1.0646x over previous
//
#include <hip/hip_runtime.h>
#include <stdint.h>

// Dims: msa[1,S,R,M] fp32 ; left_w/right_w[M,C] ; out_w[C*C,CZ] ; out[1,R,R,CZ] fp32
#define S_DIM 128
#define R_DIM 256
#define M_DIM 256
#define C_DIM 32
#define CZ_DIM 128
#define K2_DIM 1024  // C*C

typedef _Float16 f16;
typedef _Float16 f16x4 __attribute__((ext_vector_type(4)));
typedef _Float16 f16x8 __attribute__((ext_vector_type(8)));
typedef float f32x4 __attribute__((ext_vector_type(4)));
typedef float f32x16 __attribute__((ext_vector_type(16)));

// ---------------------------------------------------------------------------
// prep: weights -> f16.
//  wt_l/wt_r[c][m] (proj A-operands).
//  wt2 = out_w in stage2 B-FRAGMENT-MAJOR order (see R8 journal): coalesced
//  1KB-per-wave loads in fuse phase 3.
// ---------------------------------------------------------------------------
__global__ void prep_kernel(const float* __restrict__ lw, const float* __restrict__ rw,
                            const float* __restrict__ ow,
                            f16* __restrict__ wt_l, f16* __restrict__ wt_r,
                            f16* __restrict__ wt2) {
    int idx = blockIdx.x * blockDim.x + threadIdx.x;
    int stride = gridDim.x * blockDim.x;
    for (int i = idx; i < CZ_DIM * K2_DIM; i += stride) {
        int cz = i >> 10, k2 = i & 1023;
        int c = k2 >> 5, e = k2 & 31;
        int k2p = ((e >> 2) << 7) + (c << 2) + (e & 3);
        int ntile = cz >> 5, l31 = cz & 31;
        int kk = k2p >> 4, q5 = (k2p >> 3) & 1, j = k2p & 7;
        wt2[(ntile * 64 + kk) * 512 + (l31 * 2 + q5) * 8 + j] = (f16)ow[k2 * CZ_DIM + cz];
    }
    for (int i = idx; i < C_DIM * M_DIM; i += stride) {
        int c = i >> 8, m = i & 255;
        wt_l[i] = (f16)lw[m * C_DIM + c];
        wt_r[i] = (f16)rw[m * C_DIM + c];
    }
}

// ---------------------------------------------------------------------------
// proj: per block (r, s-half): D = wt(32 c x 256 m) @ msa_r^T (256 m x 64 s).
// left_t[(r*32+c)][s] row-major; rt2 in stage1 A-fragment-major order.
// ---------------------------------------------------------------------------
__global__ __launch_bounds__(256, 4)
void proj_kernel(const float* __restrict__ msa, const f16* __restrict__ wt_l,
                 const f16* __restrict__ wt_r,
                 f16* __restrict__ left_t, f16* __restrict__ rt2) {
    int bid = blockIdx.x;            // 512 = 256 r * 2 s-halves
    int r  = bid >> 1;
    int s0 = (bid & 1) << 6;
    int tid = threadIdx.x;
    int w = tid >> 6;
    int lane = tid & 63;
    int q = lane >> 4, li = lane & 15;

    int s_col = s0 + w * 16 + li;
    const f32x4* bp = (const f32x4*)(msa + ((size_t)s_col * R_DIM + r) * M_DIM + q * 8);

    f32x4 b[16];
#pragma unroll
    for (int ks = 0; ks < 8; ks++) { b[2 * ks] = bp[ks * 8]; b[2 * ks + 1] = bp[ks * 8 + 1]; }

    f32x4 aL0 = {0,0,0,0}, aL1 = {0,0,0,0}, aR0 = {0,0,0,0}, aR1 = {0,0,0,0};
#pragma unroll
    for (int ks = 0; ks < 8; ks++) {
        f16x8 bf;
#pragma unroll
        for (int u = 0; u < 4; u++) { bf[u] = (f16)b[2*ks][u]; bf[4 + u] = (f16)b[2*ks+1][u]; }
        const f16* a0 = wt_l + li * M_DIM + ks * 32 + q * 8;
        const f16* a1 = wt_r + li * M_DIM + ks * 32 + q * 8;
        f16x8 al0 = *(const f16x8*)(a0);
        f16x8 al1 = *(const f16x8*)(a0 + 16 * M_DIM);
        f16x8 ar0 = *(const f16x8*)(a1);
        f16x8 ar1 = *(const f16x8*)(a1 + 16 * M_DIM);
        aL0 = __builtin_amdgcn_mfma_f32_16x16x32_f16(al0, bf, aL0, 0, 0, 0);
        aL1 = __builtin_amdgcn_mfma_f32_16x16x32_f16(al1, bf, aL1, 0, 0, 0);
        aR0 = __builtin_amdgcn_mfma_f32_16x16x32_f16(ar0, bf, aR0, 0, 0, 0);
        aR1 = __builtin_amdgcn_mfma_f32_16x16x32_f16(ar1, bf, aR1, 0, 0, 0);
    }
    int ks_s = s_col >> 4, q5_s = (s_col >> 3) & 1, j_s = s_col & 7;
    int sbase = (r * 8 + ks_s) * 512 + q5_s * 8 + j_s;
#pragma unroll
    for (int reg = 0; reg < 4; reg++) {
        int c0 = q * 4 + reg;
        left_t[(r * C_DIM + c0) * S_DIM + s_col]      = (f16)aL0[reg];
        left_t[(r * C_DIM + c0 + 16) * S_DIM + s_col] = (f16)aL1[reg];
        rt2[sbase + c0 * 16]        = (f16)aR0[reg];
        rt2[sbase + (c0 + 16) * 16] = (f16)aR1[reg];
    }
}

// ---------------------------------------------------------------------------
// fuse_kernel v5: v4 + deep-pipelined phase 3 (3-deep W ring, 2-deep af ring,
// fully unrolled so ring slots are renamed, no register copies).
// ---------------------------------------------------------------------------
__global__ __launch_bounds__(512, 4)
void fuse_kernel(const f16* __restrict__ left_t, const f16* __restrict__ rt2,
                 const f16* __restrict__ wt2, float* __restrict__ out) {
    __shared__ __align__(16) char lds[65536];
    f16* Ls = (f16*)lds;

    int bid = blockIdx.x;        // 2048 = 32 br * 64 bt
    int br = bid >> 6, bt = bid & 63;
    int tid = threadIdx.x;
    int w = tid >> 6, lane = tid & 63;
    int q5 = lane >> 5, l31 = lane & 31, lx = lane & 15;

    const f16* Lg = left_t + (size_t)br * 32768;    // 256 rc rows x 128 s

    // ---- phase 0: afr prefetch (coalesced fragment-major) + stage left ----
    int t_tile = w & 3, rg4 = w >> 2;
    int g = bt * 4 + t_tile;
    const f16* ap = rt2 + (size_t)g * 4096 + (l31 * 2 + q5) * 8;
    f16x8 afr[8];
#pragma unroll
    for (int ks = 0; ks < 8; ks++) afr[ks] = *(const f16x8*)(ap + ks * 512);

#pragma unroll
    for (int it = 0; it < 8; it++) {
        int G = it * 512 + tid, row = G >> 4, ch = G & 15;
        f16x8 v = *(const f16x8*)(Lg + G * 8);
        *(f16x8*)(Ls + row * 128 + ((ch ^ (row & 15)) << 3)) = v;
    }
    __syncthreads();

    // ---- phase 1: stage1 MFMAs (D[te][rc]) ----
    f32x16 acc[4] = {};
#pragma unroll
    for (int i = 0; i < 4; i++) {
        const f16* bbase = Ls + ((rg4 * 4 + i) * 32 + l31) * 128;
#pragma unroll
        for (int ks = 0; ks < 8; ks++) {
            f16x8 bfr = *(const f16x8*)(bbase + (((2 * ks + q5) ^ lx) << 3));
            acc[i] = __builtin_amdgcn_mfma_f32_32x32x16_f16(afr[ks], bfr, acc[i], 0, 0, 0);
        }
    }

    // ---- W group 0: issue pre-barrier (hidden by phase 2 + barrier) ----
    int ntile = w & 3, kh = w >> 2;
    const f16* wbase = wt2 + (size_t)(ntile * 64 + kh * 32) * 512 + (l31 * 2 + q5) * 8;
    f16x8 wfg[8][4];
#pragma unroll
    for (int u = 0; u < 4; u++) wfg[0][u] = *(const f16x8*)(wbase + u * 512);

    __syncthreads();   // protects LDS overlay (phase2 writes over Ls)

    // ---- phase 2: write outer to LDS ----
    int chc = l31 >> 1, bsub = 8 * (l31 & 1);
#pragma unroll
    for (int i = 0; i < 4; i++) {
        int p = (rg4 * 4 + i) * 4 + t_tile;         // pair row 0..31
        char* prow = lds + p * 2048;
#pragma unroll
        for (int rg = 0; rg < 4; rg++) {
            int ch = (2 * rg + q5) * 16 + chc;
            int phys = (ch + p) & 127;
            f16x4 h = {(f16)acc[i][4 * rg], (f16)acc[i][4 * rg + 1],
                       (f16)acc[i][4 * rg + 2], (f16)acc[i][4 * rg + 3]};
            *(f16x4*)(prow + phys * 16 + bsub) = h;
        }
    }
    __syncthreads();

    // ---- phase 3: stage2, fully unrolled, 3-deep W ring + 2-deep af ring ----
    const char* lbase = lds + l31 * 2048;           // p = l31 (2048-aligned rows)
    int base = 64 * kh + q5 + l31;                  // k-chunk index before wrap
    f16x8 afg[8][4];
    f32x16 accA = {}, accB = {};
#pragma unroll
    for (int gg = 0; gg < 8; gg++) {
        if (gg == 0) {
            // fill rings: W groups 1,2 ; af groups 0,1
#pragma unroll
            for (int u = 0; u < 4; u++) wfg[1][u] = *(const f16x8*)(wbase + (4 + u) * 512);
#pragma unroll
            for (int u = 0; u < 4; u++) wfg[2][u] = *(const f16x8*)(wbase + (8 + u) * 512);
#pragma unroll
            for (int u = 0; u < 4; u++)
                afg[0][u] = *(const f16x8*)(lbase + (((base + 2 * u) & 127) << 4));
#pragma unroll
            for (int u = 0; u < 4; u++)
                afg[1][u] = *(const f16x8*)(lbase + (((base + 8 + 2 * u) & 127) << 4));
        } else {
            if (gg + 2 < 8) {
#pragma unroll
                for (int u = 0; u < 4; u++)
                    wfg[gg + 2][u] = *(const f16x8*)(wbase + ((gg + 2) * 4 + u) * 512);
            }
            if (gg + 1 < 8) {
#pragma unroll
                for (int u = 0; u < 4; u++)
                    afg[gg + 1][u] = *(const f16x8*)(lbase + (((base + (gg + 1) * 8 + 2 * u) & 127) << 4));
            }
        }
        accA = __builtin_amdgcn_mfma_f32_32x32x16_f16(afg[gg][0], wfg[gg][0], accA, 0, 0, 0);
        accB = __builtin_amdgcn_mfma_f32_32x32x16_f16(afg[gg][1], wfg[gg][1], accB, 0, 0, 0);
        accA = __builtin_amdgcn_mfma_f32_32x32x16_f16(afg[gg][2], wfg[gg][2], accA, 0, 0, 0);
        accB = __builtin_amdgcn_mfma_f32_32x32x16_f16(afg[gg][3], wfg[gg][3], accB, 0, 0, 0);
    }
    f32x16 acc2;
#pragma unroll
    for (int v = 0; v < 16; v++) acc2[v] = accA[v] + accB[v];
    __syncthreads();

    // ---- k-reduction: wave w+4 -> LDS, wave w adds ----
    if (w >= 4) {
        char* rb = lds + (w - 4) * 4096 + lane * 64;
#pragma unroll
        for (int u = 0; u < 4; u++) {
            f32x4 part = {acc2[4 * u], acc2[4 * u + 1], acc2[4 * u + 2], acc2[4 * u + 3]};
            *(f32x4*)(rb + u * 16) = part;
        }
    }
    __syncthreads();
    if (w < 4) {
        const char* rb = lds + w * 4096 + lane * 64;
#pragma unroll
        for (int u = 0; u < 4; u++) {
            f32x4 part = *(const f32x4*)(rb + u * 16);
#pragma unroll
            for (int v = 0; v < 4; v++) acc2[4 * u + v] += part[v];
        }
        // store: D row = p = (reg&3)+8*(reg>>2)+4*q5 ; col = cz = w*32 + l31
        int r0 = br * 8, t0 = bt * 4, cz = w * 32 + l31;
#pragma unroll
        for (int reg = 0; reg < 16; reg++) {
            int p = (reg & 3) + 8 * (reg >> 2) + 4 * q5;
            out[((size_t)((r0 + (p >> 2)) * R_DIM + t0 + (p & 3))) * CZ_DIM + cz] = acc2[reg];
        }
    }
}

// ---------------------------------------------------------------------------
extern "C" void kernel_launch(void* const* d_in, const int* in_sizes, int n_in,
                              void* d_out, int out_size, void* d_ws, size_t ws_size,
                              hipStream_t stream) {
    const float* msa = (const float*)d_in[0];
    const float* lw  = (const float*)d_in[1];
    const float* rw  = (const float*)d_in[2];
    const float* ow  = (const float*)d_in[3];
    char* ws = (char*)d_ws;
    f16* left_t = (f16*)(ws);                                   // 2 MB
    f16* rt2    = (f16*)(ws + (size_t)2 * 1024 * 1024);         // 2 MB
    f16* wt2    = (f16*)(ws + (size_t)4 * 1024 * 1024);         // 256 KB
    f16* wt_l   = (f16*)(ws + (size_t)4 * 1024 * 1024 + 262144);        // 16 KB
    f16* wt_r   = (f16*)(ws + (size_t)4 * 1024 * 1024 + 262144 + 16384);// 16 KB
    float* out  = (float*)d_out;

    prep_kernel<<<dim3(256), dim3(256), 0, stream>>>(lw, rw, ow, wt_l, wt_r, wt2);
    proj_kernel<<<dim3(512), dim3(256), 0, stream>>>(msa, wt_l, wt_r, left_t, rt2);
    fuse_kernel<<<dim3(2048), dim3(512), 0, stream>>>(left_t, rt2, wt2, out);
}